// Round 1
// baseline (1777.743 us; speedup 1.0000x reference)
//
#include <hip/hip_runtime.h>
#include <hip/hip_bf16.h>
#include <math.h>

#define IGNORE_INDEX (-100)

typedef __attribute__((ext_vector_type(8))) short short8;
typedef __attribute__((ext_vector_type(4))) float f32x4;

// Problem sizes (fixed by the reference)
static const int NTOK = 2 * 4096;   // 8192 tokens
static const int DIM  = 2048;       // embed dim (K)
static const int VOC  = 32000;      // vocab (N of the GEMM)
static const int BM = 128, BN = 128, BK = 64;
static const int NVT = VOC / BN;    // 250 vocab tiles

// ---------------- helpers ----------------

__device__ inline unsigned short f2bf(float f) {
  unsigned u = __builtin_bit_cast(unsigned, f);
  u += 0x7fffu + ((u >> 16) & 1u);   // RNE to bf16
  return (unsigned short)(u >> 16);
}

__device__ inline void gload_lds16(const void* g, void* l) {
  __builtin_amdgcn_global_load_lds(
      (const __attribute__((address_space(1))) void*)g,
      (__attribute__((address_space(3))) void*)l,
      16, 0, 0);
}

// ---------------- kernel 1: fp32 -> bf16 cast ----------------

__global__ void cast_f32_bf16(const float* __restrict__ in,
                              short* __restrict__ out, long n8) {
  long i0 = (long)blockIdx.x * blockDim.x + threadIdx.x;
  long stride = (long)gridDim.x * blockDim.x;
  for (long i = i0; i < n8; i += stride) {
    const float4* p = (const float4*)(in + i * 8);
    float4 a = p[0], b = p[1];
    short8 o;
    o[0] = (short)f2bf(a.x); o[1] = (short)f2bf(a.y);
    o[2] = (short)f2bf(a.z); o[3] = (short)f2bf(a.w);
    o[4] = (short)f2bf(b.x); o[5] = (short)f2bf(b.y);
    o[6] = (short)f2bf(b.z); o[7] = (short)f2bf(b.w);
    *(short8*)(out + i * 8) = o;
  }
}

// ---------------- kernel 2: MFMA GEMM + fused row max/sumexp ----------------
// logits tile = x[m0:m0+128, :] @ W[v0:v0+128, :]^T ; writes per-row (max, sumexp)

__launch_bounds__(256)
__global__ void lce_gemm(const short* __restrict__ xb, const short* __restrict__ wb,
                         float* __restrict__ pmax, float* __restrict__ psum) {
  __shared__ __align__(16) short As[BM * BK];
  __shared__ __align__(16) short Bs[BN * BK];
  __shared__ float sm_m[2][BM];
  __shared__ float sm_s[2][BM];

  const int vt = blockIdx.x;
  const int mt = blockIdx.y;
  const int m0 = mt * BM;
  const int v0 = vt * BN;
  const int tid = threadIdx.x;
  const int lane = tid & 63;
  const int w = tid >> 6;
  const int wr = w >> 1, wc = w & 1;
  const int li = lane & 15, lg = lane >> 4;

  f32x4 acc[4][4];
  const f32x4 z = {0.f, 0.f, 0.f, 0.f};
#pragma unroll
  for (int i = 0; i < 4; ++i)
#pragma unroll
    for (int j = 0; j < 4; ++j) acc[i][j] = z;

  // staging geometry: 16 chunks of 1 KiB per tile; wave w stages chunks w*4..w*4+3
  const int ric = lane >> 3;          // row in chunk 0..7
  const int kcol = (lane & 7) * 8;    // k element 0..56
  const int ca0 = w * 4;
  long aBase[4], bBase[4];
#pragma unroll
  for (int q = 0; q < 4; ++q) {
    aBase[q] = (long)(m0 + (ca0 + q) * 8 + ric) * DIM + kcol;
    bBase[q] = (long)(v0 + (ca0 + q) * 8 + ric) * DIM + kcol;
  }

  const short* aFragBase = &As[(wr * 64 + li) * BK + lg * 8];
  const short* bFragBase = &Bs[(wc * 64 + li) * BK + lg * 8];

  for (int kt = 0; kt < DIM; kt += BK) {
    __syncthreads();   // previous tile's ds_reads done before overwrite
#pragma unroll
    for (int q = 0; q < 4; ++q) {
      gload_lds16(xb + aBase[q] + kt, (char*)As + (ca0 + q) * 1024);
      gload_lds16(wb + bBase[q] + kt, (char*)Bs + (ca0 + q) * 1024);
    }
    __syncthreads();   // drains vmcnt: staged data visible
#pragma unroll
    for (int kk = 0; kk < BK; kk += 32) {
      short8 a[4], b[4];
#pragma unroll
      for (int i = 0; i < 4; ++i)
        a[i] = *(const short8*)(aFragBase + i * 16 * BK + kk);
#pragma unroll
      for (int j = 0; j < 4; ++j)
        b[j] = *(const short8*)(bFragBase + j * 16 * BK + kk);
#pragma unroll
      for (int i = 0; i < 4; ++i)
#pragma unroll
        for (int j = 0; j < 4; ++j)
          acc[i][j] = __builtin_amdgcn_mfma_f32_16x16x32_bf16(a[i], b[j], acc[i][j], 0, 0, 0);
    }
  }

  // epilogue: per-row max and sum(exp) over this tile's 128 columns.
  // C/D layout (verified m89): col = lane&15, row = (lane>>4)*4 + reg
#pragma unroll
  for (int i = 0; i < 4; ++i) {
#pragma unroll
    for (int r = 0; r < 4; ++r) {
      float m = fmaxf(fmaxf(acc[i][0][r], acc[i][1][r]),
                      fmaxf(acc[i][2][r], acc[i][3][r]));
#pragma unroll
      for (int mk = 1; mk < 16; mk <<= 1) m = fmaxf(m, __shfl_xor(m, mk));
      float s = __expf(acc[i][0][r] - m) + __expf(acc[i][1][r] - m) +
                __expf(acc[i][2][r] - m) + __expf(acc[i][3][r] - m);
#pragma unroll
      for (int mk = 1; mk < 16; mk <<= 1) s += __shfl_xor(s, mk);
      if (li == 0) {
        int row = wr * 64 + i * 16 + lg * 4 + r;
        sm_m[wc][row] = m;
        sm_s[wc][row] = s;
      }
    }
  }
  __syncthreads();
  if (tid < BM) {
    float ma = sm_m[0][tid], mb = sm_m[1][tid];
    float gm = fmaxf(ma, mb);
    float gs = sm_s[0][tid] * __expf(ma - gm) + sm_s[1][tid] * __expf(mb - gm);
    long row = (long)(m0 + tid);
    pmax[row * NVT + vt] = gm;
    psum[row * NVT + vt] = gs;
  }
}

// ---------------- kernel 3: per-token LSE combine + exact fp32 target dot ----------------

__global__ void token_reduce(const float* __restrict__ x, const float* __restrict__ wgt,
                             const int* __restrict__ tgt,
                             const float* __restrict__ pmax, const float* __restrict__ psum,
                             float* __restrict__ nll, float* __restrict__ validf) {
  const int n = blockIdx.x;
  const int tid = threadIdx.x;
  const int lane = tid & 63;
  const int w = tid >> 6;
  __shared__ float smr[4];

  const int t = tgt[n];
  const bool valid = (t != IGNORE_INDEX);
  const int ts = valid ? t : 0;

  // exact fp32 target logit
  const float4* xr = (const float4*)(x + (long)n * DIM);
  const float4* wr = (const float4*)(wgt + (long)ts * DIM);
  float d = 0.f;
  for (int i = tid; i < DIM / 4; i += blockDim.x) {
    float4 a = xr[i], b = wr[i];
    d += a.x * b.x + a.y * b.y + a.z * b.z + a.w * b.w;
  }

  // LSE over 250 partials
  float m = (tid < NVT) ? pmax[(long)n * NVT + tid] : -INFINITY;
  float t1 = m;
#pragma unroll
  for (int mk = 1; mk < 64; mk <<= 1) t1 = fmaxf(t1, __shfl_xor(t1, mk));
  if (lane == 0) smr[w] = t1;
  __syncthreads();
  const float gm = fmaxf(fmaxf(smr[0], smr[1]), fmaxf(smr[2], smr[3]));
  __syncthreads();

  float se = (tid < NVT) ? psum[(long)n * NVT + tid] * __expf(m - gm) : 0.f;
#pragma unroll
  for (int mk = 1; mk < 64; mk <<= 1) se += __shfl_xor(se, mk);
  if (lane == 0) smr[w] = se;
  __syncthreads();
  const float gs = smr[0] + smr[1] + smr[2] + smr[3];
  __syncthreads();

#pragma unroll
  for (int mk = 1; mk < 64; mk <<= 1) d += __shfl_xor(d, mk);
  if (lane == 0) smr[w] = d;
  __syncthreads();
  const float gd = smr[0] + smr[1] + smr[2] + smr[3];

  if (tid == 0) {
    nll[n] = valid ? (gm + logf(gs) - gd) : 0.f;
    validf[n] = valid ? 1.f : 0.f;
  }
}

// ---------------- kernel 4: deterministic final mean ----------------

__global__ void final_reduce(const float* __restrict__ nll, const float* __restrict__ validf,
                             float* __restrict__ out, int n) {
  const int tid = threadIdx.x;
  const int lane = tid & 63;
  const int w = tid >> 6;
  __shared__ float sm1[4], sm2[4];
  float s = 0.f, c = 0.f;
  for (int i = tid; i < n; i += blockDim.x) { s += nll[i]; c += validf[i]; }
#pragma unroll
  for (int mk = 1; mk < 64; mk <<= 1) { s += __shfl_xor(s, mk); c += __shfl_xor(c, mk); }
  if (lane == 0) { sm1[w] = s; sm2[w] = c; }
  __syncthreads();
  if (tid == 0) {
    float ts = sm1[0] + sm1[1] + sm1[2] + sm1[3];
    float tc = sm2[0] + sm2[1] + sm2[2] + sm2[3];
    out[0] = ts / fmaxf(tc, 1.0f);
  }
}

// ---------------- launch ----------------

extern "C" void kernel_launch(void* const* d_in, const int* in_sizes, int n_in,
                              void* d_out, int out_size, void* d_ws, size_t ws_size,
                              hipStream_t stream) {
  const float* x = (const float*)d_in[0];     // [8192, 2048] fp32
  const float* wgt = (const float*)d_in[1];   // [32000, 2048] fp32
  const int* tgt = (const int*)d_in[2];       // [8192] int
  float* out = (float*)d_out;

  char* ws = (char*)d_ws;
  const size_t xb_off = 0;
  const size_t wb_off = (size_t)NTOK * DIM * 2;                    //  33,554,432
  const size_t pm_off = wb_off + (size_t)VOC * DIM * 2;            // 164,626,432
  const size_t ps_off = pm_off + (size_t)NTOK * NVT * 4;           // 172,818,432
  const size_t nl_off = ps_off + (size_t)NTOK * NVT * 4;           // 181,010,432
  const size_t vf_off = nl_off + (size_t)NTOK * 4;
  const size_t needed = vf_off + (size_t)NTOK * 4;
  if (ws_size < needed) return;  // workspace too small: fail visibly

  short* xb = (short*)(ws + xb_off);
  short* wb = (short*)(ws + wb_off);
  float* pmax = (float*)(ws + pm_off);
  float* psum = (float*)(ws + ps_off);
  float* nllv = (float*)(ws + nl_off);
  float* vldf = (float*)(ws + vf_off);

  cast_f32_bf16<<<2048, 256, 0, stream>>>(x, xb, (long)NTOK * DIM / 8);
  cast_f32_bf16<<<4096, 256, 0, stream>>>(wgt, wb, (long)VOC * DIM / 8);

  dim3 grid(NVT, NTOK / BM);  // 250 x 64
  lce_gemm<<<grid, 256, 0, stream>>>(xb, wb, pmax, psum);

  token_reduce<<<NTOK, 256, 0, stream>>>(x, wgt, tgt, pmax, psum, nllv, vldf);
  final_reduce<<<1, 256, 0, stream>>>(nllv, vldf, out, NTOK);
}

// Round 2
// 1271.171 us; speedup vs baseline: 1.3985x; 1.3985x over previous
//
#include <hip/hip_runtime.h>
#include <hip/hip_bf16.h>
#include <math.h>

#define IGNORE_INDEX (-100)

typedef __attribute__((ext_vector_type(8))) short short8;
typedef __attribute__((ext_vector_type(4))) float f32x4;

// Problem sizes (fixed by the reference)
static const int NTOK = 2 * 4096;   // 8192 tokens (GEMM M)
static const int DIM  = 2048;       // embed dim (GEMM K)
static const int VOC  = 32000;      // vocab (GEMM N)
static const int BM = 256, BN = 256;
static const int KH = 32;           // K per phase
static const int NPH = DIM / KH;    // 64 phases
static const int NVT = VOC / BN;    // 125 vocab tiles
static const int MT  = NTOK / BM;   // 32 m tiles

// ---------------- helpers ----------------

__device__ inline unsigned short f2bf(float f) {
  unsigned u = __builtin_bit_cast(unsigned, f);
  u += 0x7fffu + ((u >> 16) & 1u);   // RNE to bf16
  return (unsigned short)(u >> 16);
}

__device__ inline void gload_lds16(const void* g, void* l) {
  __builtin_amdgcn_global_load_lds(
      (const __attribute__((address_space(1))) void*)g,
      (__attribute__((address_space(3))) void*)l,
      16, 0, 0);
}

// ---------------- kernel 1: fp32 -> bf16 cast ----------------

__global__ void cast_f32_bf16(const float* __restrict__ in,
                              short* __restrict__ out, long n8) {
  long i0 = (long)blockIdx.x * blockDim.x + threadIdx.x;
  long stride = (long)gridDim.x * blockDim.x;
  for (long i = i0; i < n8; i += stride) {
    const float4* p = (const float4*)(in + i * 8);
    float4 a = p[0], b = p[1];
    short8 o;
    o[0] = (short)f2bf(a.x); o[1] = (short)f2bf(a.y);
    o[2] = (short)f2bf(a.z); o[3] = (short)f2bf(a.w);
    o[4] = (short)f2bf(b.x); o[5] = (short)f2bf(b.y);
    o[6] = (short)f2bf(b.z); o[7] = (short)f2bf(b.w);
    *(short8*)(out + i * 8) = o;
  }
}

// ---------------- kernel 2: 256x256 phase-pipelined MFMA GEMM + fused row max/sumexp ----------------
// LDS: A: 4 slots of [256][32] bf16 (16KB each, 64KB), B: same at +64KB. 128KB dynamic.
// Swizzle involution on byte offsets within a 16KB slot: b ^= ((b>>8)&3)<<4.
// Staged via global_load_lds (linear dest) with pre-swizzled global source; ds_read applies same XOR.

#define VM8  asm volatile("s_waitcnt vmcnt(8)" ::: "memory")
#define VM4  asm volatile("s_waitcnt vmcnt(4)" ::: "memory")
#define VM0  asm volatile("s_waitcnt vmcnt(0)" ::: "memory")
#define VMNONE do {} while (0)
#define BARRIER asm volatile("s_barrier" ::: "memory")

#define STAGE_ADV(SLOT) do { \
  char* _dA = stA + (SLOT) * 16384; \
  char* _dB = stB + (SLOT) * 16384; \
  gload_lds16(aP0, _dA); \
  gload_lds16(aP1, _dA + 1024); \
  gload_lds16(bP0, _dB); \
  gload_lds16(bP1, _dB + 1024); \
  aP0 += KH; aP1 += KH; bP0 += KH; bP1 += KH; \
} while (0)

#define PHASE(N, DOSTAGE, VMWAIT) do { \
  const int _slot = (N) & 3; \
  const char* _Ap = smA + _slot * 16384 + aOff; \
  const char* _Bp = smB + _slot * 16384 + bOff; \
  short8 _a[8], _b[4]; \
  _Pragma("unroll") \
  for (int _i = 0; _i < 8; ++_i) _a[_i] = *(const short8*)(_Ap + _i * 1024); \
  _Pragma("unroll") \
  for (int _j = 0; _j < 4; ++_j) _b[_j] = *(const short8*)(_Bp + _j * 1024); \
  if (DOSTAGE) { STAGE_ADV(((N) + 3) & 3); } \
  BARRIER; \
  __builtin_amdgcn_s_setprio(1); \
  _Pragma("unroll") \
  for (int _i = 0; _i < 8; ++_i) \
    _Pragma("unroll") \
    for (int _j = 0; _j < 4; ++_j) \
      acc[_i][_j] = __builtin_amdgcn_mfma_f32_16x16x32_bf16(_a[_i], _b[_j], acc[_i][_j], 0, 0, 0); \
  __builtin_amdgcn_s_setprio(0); \
  asm volatile("s_waitcnt lgkmcnt(0)" ::: "memory"); \
  VMWAIT; \
  BARRIER; \
} while (0)

__launch_bounds__(512, 2)
__global__ void lce_gemm(const short* __restrict__ xb, const short* __restrict__ wb,
                         float* __restrict__ pmax, float* __restrict__ psum) {
  extern __shared__ char smem[];
  char* smA = smem;
  char* smB = smem + 65536;

  // XCD-aware swizzle (nwg = 4000, divisible by 8) then mt-minor mapping
  const int nwg = NVT * MT;            // 4000
  const int cpx = nwg >> 3;            // 500
  const int bid = blockIdx.x;
  const int swz = (bid & 7) * cpx + (bid >> 3);
  const int vt = swz / MT;
  const int mt = swz % MT;
  const int m0 = mt * BM;
  const int v0 = vt * BN;

  const int tid = threadIdx.x;
  const int lane = tid & 63;
  const int w = tid >> 6;              // 0..7
  const int wr = w >> 2, wc = w & 3;   // 2 x 4 wave grid
  const int li = lane & 15, lg = lane >> 4;

  f32x4 acc[8][4];
  const f32x4 z = {0.f, 0.f, 0.f, 0.f};
#pragma unroll
  for (int i = 0; i < 8; ++i)
#pragma unroll
    for (int j = 0; j < 4; ++j) acc[i][j] = z;

  // ---- staging source addresses (pre-swizzled global) ----
  // physical 16B unit U in [0,1024) per slot; logical V = U ^ ((U>>4)&3); row=V>>2, ks=V&3
  int rowS[2], ksS[2];
#pragma unroll
  for (int q = 0; q < 2; ++q) {
    int U = w * 128 + q * 64 + lane;
    int V = U ^ ((U >> 4) & 3);
    rowS[q] = V >> 2;
    ksS[q] = V & 3;
  }
  const short* aP0 = xb + (long)(m0 + rowS[0]) * DIM + ksS[0] * 8;
  const short* aP1 = xb + (long)(m0 + rowS[1]) * DIM + ksS[1] * 8;
  const short* bP0 = wb + (long)(v0 + rowS[0]) * DIM + ksS[0] * 8;
  const short* bP1 = wb + (long)(v0 + rowS[1]) * DIM + ksS[1] * 8;
  char* stA = smA + w * 2048;
  char* stB = smB + w * 2048;

  // ---- ds_read fragment offsets (swizzled physical byte within slot) ----
  const int La = (wr * 128 + li) * 64 + lg * 16;
  const int aOff = La ^ (((La >> 8) & 3) << 4);
  const int Lb = (wc * 64 + li) * 64 + lg * 16;
  const int bOff = Lb ^ (((Lb >> 8) & 3) << 4);

  // ---- prologue: stage phases 0,1,2 (12 loads/wave), ensure phase 0 ready ----
  STAGE_ADV(0);
  STAGE_ADV(1);
  STAGE_ADV(2);
  VM8;
  BARRIER;

  // ---- main loop: 64 phases of K=32; counted vmcnt(8); tail drains 8->4->0 ----
#pragma unroll 1
  for (int n = 0; n < NPH - 3; ++n) {   // n = 0..60, stages phases 3..63
    PHASE(n, 1, VM8);
  }
  PHASE(NPH - 3, 0, VM4);
  PHASE(NPH - 2, 0, VM0);
  PHASE(NPH - 1, 0, VMNONE);

  // ---- epilogue: per-row max & sum(exp) over this tile's 256 cols ----
  // C/D layout: col = li, row(within 16x16) = lg*4 + r; wave tile rows wr*128+i*16, cols wc*64+j*16
  float* sm_m = (float*)smem;          // [4][256]  (reuses slot A memory; loop fully drained)
  float* sm_s = (float*)(smem + 4096); // [4][256]
#pragma unroll
  for (int i = 0; i < 8; ++i) {
#pragma unroll
    for (int r = 0; r < 4; ++r) {
      float m = fmaxf(fmaxf(acc[i][0][r], acc[i][1][r]),
                      fmaxf(acc[i][2][r], acc[i][3][r]));
#pragma unroll
      for (int mk = 1; mk < 16; mk <<= 1) m = fmaxf(m, __shfl_xor(m, mk));
      float s = __expf(acc[i][0][r] - m) + __expf(acc[i][1][r] - m) +
                __expf(acc[i][2][r] - m) + __expf(acc[i][3][r] - m);
#pragma unroll
      for (int mk = 1; mk < 16; mk <<= 1) s += __shfl_xor(s, mk);
      if (li == 0) {
        int R = wr * 128 + i * 16 + lg * 4 + r;
        sm_m[wc * 256 + R] = m;
        sm_s[wc * 256 + R] = s;
      }
    }
  }
  __syncthreads();
  if (tid < BM) {
    float ma = sm_m[tid], mb = sm_m[256 + tid], mc = sm_m[512 + tid], md = sm_m[768 + tid];
    float gm = fmaxf(fmaxf(ma, mb), fmaxf(mc, md));
    float gs = sm_s[tid] * __expf(ma - gm) + sm_s[256 + tid] * __expf(mb - gm) +
               sm_s[512 + tid] * __expf(mc - gm) + sm_s[768 + tid] * __expf(md - gm);
    long row = (long)(m0 + tid);
    pmax[row * NVT + vt] = gm;
    psum[row * NVT + vt] = gs;
  }
}

// ---------------- kernel 3: per-token LSE combine + exact fp32 target dot ----------------

__global__ void token_reduce(const float* __restrict__ x, const float* __restrict__ wgt,
                             const int* __restrict__ tgt,
                             const float* __restrict__ pmax, const float* __restrict__ psum,
                             float* __restrict__ nll, float* __restrict__ validf) {
  const int n = blockIdx.x;
  const int tid = threadIdx.x;
  const int lane = tid & 63;
  const int w = tid >> 6;
  __shared__ float smr[4];

  const int t = tgt[n];
  const bool valid = (t != IGNORE_INDEX);
  const int ts = valid ? t : 0;

  // exact fp32 target logit
  const float4* xr = (const float4*)(x + (long)n * DIM);
  const float4* wr = (const float4*)(wgt + (long)ts * DIM);
  float d = 0.f;
  for (int i = tid; i < DIM / 4; i += blockDim.x) {
    float4 a = xr[i], b = wr[i];
    d += a.x * b.x + a.y * b.y + a.z * b.z + a.w * b.w;
  }

  // LSE over 125 partials
  float m = (tid < NVT) ? pmax[(long)n * NVT + tid] : -INFINITY;
  float t1 = m;
#pragma unroll
  for (int mk = 1; mk < 64; mk <<= 1) t1 = fmaxf(t1, __shfl_xor(t1, mk));
  if (lane == 0) smr[w] = t1;
  __syncthreads();
  const float gm = fmaxf(fmaxf(smr[0], smr[1]), fmaxf(smr[2], smr[3]));
  __syncthreads();

  float se = (tid < NVT) ? psum[(long)n * NVT + tid] * __expf(m - gm) : 0.f;
#pragma unroll
  for (int mk = 1; mk < 64; mk <<= 1) se += __shfl_xor(se, mk);
  if (lane == 0) smr[w] = se;
  __syncthreads();
  const float gs = smr[0] + smr[1] + smr[2] + smr[3];
  __syncthreads();

#pragma unroll
  for (int mk = 1; mk < 64; mk <<= 1) d += __shfl_xor(d, mk);
  if (lane == 0) smr[w] = d;
  __syncthreads();
  const float gd = smr[0] + smr[1] + smr[2] + smr[3];

  if (tid == 0) {
    nll[n] = valid ? (gm + logf(gs) - gd) : 0.f;
    validf[n] = valid ? 1.f : 0.f;
  }
}

// ---------------- kernel 4: deterministic final mean ----------------

__global__ void final_reduce(const float* __restrict__ nll, const float* __restrict__ validf,
                             float* __restrict__ out, int n) {
  const int tid = threadIdx.x;
  const int lane = tid & 63;
  const int w = tid >> 6;
  __shared__ float sm1[4], sm2[4];
  float s = 0.f, c = 0.f;
  for (int i = tid; i < n; i += blockDim.x) { s += nll[i]; c += validf[i]; }
#pragma unroll
  for (int mk = 1; mk < 64; mk <<= 1) { s += __shfl_xor(s, mk); c += __shfl_xor(c, mk); }
  if (lane == 0) { sm1[w] = s; sm2[w] = c; }
  __syncthreads();
  if (tid == 0) {
    float ts = sm1[0] + sm1[1] + sm1[2] + sm1[3];
    float tc = sm2[0] + sm2[1] + sm2[2] + sm2[3];
    out[0] = ts / fmaxf(tc, 1.0f);
  }
}

// ---------------- launch ----------------

extern "C" void kernel_launch(void* const* d_in, const int* in_sizes, int n_in,
                              void* d_out, int out_size, void* d_ws, size_t ws_size,
                              hipStream_t stream) {
  const float* x = (const float*)d_in[0];     // [8192, 2048] fp32
  const float* wgt = (const float*)d_in[1];   // [32000, 2048] fp32
  const int* tgt = (const int*)d_in[2];       // [8192] int
  float* out = (float*)d_out;

  char* ws = (char*)d_ws;
  const size_t xb_off = 0;
  const size_t wb_off = (size_t)NTOK * DIM * 2;
  const size_t pm_off = wb_off + (size_t)VOC * DIM * 2;
  const size_t ps_off = pm_off + (size_t)NTOK * NVT * 4;
  const size_t nl_off = ps_off + (size_t)NTOK * NVT * 4;
  const size_t vf_off = nl_off + (size_t)NTOK * 4;
  const size_t needed = vf_off + (size_t)NTOK * 4;
  if (ws_size < needed) return;  // workspace too small: fail visibly

  short* xb = (short*)(ws + xb_off);
  short* wb = (short*)(ws + wb_off);
  float* pmax = (float*)(ws + pm_off);
  float* psum = (float*)(ws + ps_off);
  float* nllv = (float*)(ws + nl_off);
  float* vldf = (float*)(ws + vf_off);

  cast_f32_bf16<<<2048, 256, 0, stream>>>(x, xb, (long)NTOK * DIM / 8);
  cast_f32_bf16<<<4096, 256, 0, stream>>>(wgt, wb, (long)VOC * DIM / 8);

  (void)hipFuncSetAttribute((const void*)lce_gemm,
                            hipFuncAttributeMaxDynamicSharedMemorySize, 131072);
  lce_gemm<<<NVT * MT, 512, 131072, stream>>>(xb, wb, pmax, psum);

  token_reduce<<<NTOK, 256, 0, stream>>>(x, wgt, tgt, pmax, psum, nllv, vldf);
  final_reduce<<<1, 256, 0, stream>>>(nllv, vldf, out, NTOK);
}